// Round 3
// baseline (1016.925 us; speedup 1.0000x reference)
//
#include <hip/hip_runtime.h>
#include <hip/hip_bf16.h>

#define NN 50000
#define EE 800000
#define FIN 500
#define H1D 300
#define H2D 100
#define CC 16

// ---------- dtype-flexible load helpers ----------
__device__ __forceinline__ float ldf(const void* p, size_t i, int isbf16) {
    return isbf16 ? __bfloat162float(((const __hip_bfloat16*)p)[i])
                  : ((const float*)p)[i];
}
__device__ __forceinline__ int ld_src(const int* ei, int e, int is64) {
    return is64 ? ei[2 * (size_t)e] : ei[e];
}
__device__ __forceinline__ int ld_dst(const int* ei, int e, int is64) {
    return is64 ? ei[2 * ((size_t)EE + e)] : ei[(size_t)EE + e];
}

// ---------- dtype sniffing ----------
// flags[0]=1 if floats are stored as bf16, 0 if fp32.
// flags[1]=1 if edge_index is int64, 0 if int32.
__global__ void k_sniff(const unsigned short* __restrict__ xw,
                        const unsigned int* __restrict__ ew,
                        int* __restrict__ flags) {
    __shared__ int c_sane, c_zero;
    if (threadIdx.x == 0) { c_sane = 0; c_zero = 0; }
    __syncthreads();
    int t = threadIdx.x;  // 256 threads, 4 samples each
    int sane = 0, zer = 0;
    for (int j = 0; j < 4; j++) {
        unsigned short w = xw[t * 4 + j];
        int ex = (w >> 7) & 0xFF;
        if (w == 0 || (ex >= 100 && ex <= 150)) sane++;     // plausible bf16 of N(0,1)
        if (ew[2 * (t * 4 + j) + 1] == 0u) zer++;           // int64 high words
    }
    atomicAdd(&c_sane, sane);
    atomicAdd(&c_zero, zer);
    __syncthreads();
    if (threadIdx.x == 0) {
        flags[0] = (c_sane > 820) ? 1 : 0;  // >80% of 1024
        flags[1] = (c_zero > 512) ? 1 : 0;  // >50% of 1024
    }
}

// ---------- degree / CSR build ----------
__global__ void k_zero_cnt(int* __restrict__ cnt) {
    int i = blockIdx.x * blockDim.x + threadIdx.x;
    if (i < NN) cnt[i] = 0;
}

__global__ void k_hist(const int* __restrict__ ei, int* __restrict__ cnt,
                       const int* __restrict__ flags) {
    int e = blockIdx.x * blockDim.x + threadIdx.x;
    int is64 = flags[1];
    if (e < EE) {
        int d = ld_dst(ei, e, is64);
        if ((unsigned)d < NN) atomicAdd(&cnt[d], 1);
    }
}

__global__ void k_dinv(const int* __restrict__ cnt, float* __restrict__ dinv) {
    int i = blockIdx.x * blockDim.x + threadIdx.x;
    if (i < NN) dinv[i] = rsqrtf((float)cnt[i] + 1.0f);  // +1 self loop, deg>=1
}

__global__ __launch_bounds__(1024) void k_scan(int* __restrict__ cnt, int* __restrict__ row_ptr) {
    const int T = 1024;
    const int chunk = (NN + T - 1) / T;  // 49
    int t = threadIdx.x;
    int lo = t * chunk;
    int hi = lo + chunk; if (hi > NN) hi = NN; if (lo > NN) lo = NN;
    int s = 0;
    for (int i = lo; i < hi; i++) s += cnt[i];
    __shared__ int sums[T];
    sums[t] = s;
    __syncthreads();
    for (int off = 1; off < T; off <<= 1) {
        int v = (t >= off) ? sums[t - off] : 0;
        __syncthreads();
        sums[t] += v;
        __syncthreads();
    }
    int run = sums[t] - s;  // exclusive prefix
    for (int i = lo; i < hi; i++) {
        int c = cnt[i];
        row_ptr[i] = run;
        run += c;
        cnt[i] = 0;  // reuse cnt as fill counter for scatter
    }
    if (t == T - 1) row_ptr[NN] = run;
}

__global__ void k_scatter(const int* __restrict__ ei, const int* __restrict__ row_ptr,
                          int* __restrict__ fill, int* __restrict__ csr_src,
                          const int* __restrict__ flags) {
    int e = blockIdx.x * blockDim.x + threadIdx.x;
    int is64 = flags[1];
    if (e < EE) {
        int s = ld_src(ei, e, is64);
        int d = ld_dst(ei, e, is64);
        if ((unsigned)d < NN) {
            int pos = row_ptr[d] + atomicAdd(&fill[d], 1);
            csr_src[pos] = s;
        }
    }
}

// ---------- tiled GEMM: C[M,Nn] = A[M,K] @ B[K,Nn]  (+bias)(*dinv[m])(relu) ----------
// A_DYN: A dtype follows flags[0]; otherwise A is fp32 scratch.
template <bool A_DYN, bool RELU, bool SCALE>
__global__ __launch_bounds__(256) void k_gemm(const void* __restrict__ A,
                                              const void* __restrict__ B,
                                              const void* __restrict__ bias,
                                              const float* __restrict__ dinv,
                                              float* __restrict__ C,
                                              int M, int K, int Nn,
                                              const int* __restrict__ flags) {
    __shared__ float As[16][68];  // [k][m], padded
    __shared__ float Bs[16][68];  // [k][n]
    const int bf = flags[0];
    const int tid = threadIdx.x;
    const int m0 = blockIdx.x * 64, n0 = blockIdx.y * 64;
    const int tx = tid & 15;   // n group (4 cols)
    const int ty = tid >> 4;   // m group (4 rows)
    float acc[4][4] = {};

    for (int kc = 0; kc < K; kc += 16) {
#pragma unroll
        for (int j = 0; j < 4; j++) {
            int idx = tid + j * 256;
            int kk = idx & 15, mm = idx >> 4;
            int gm = m0 + mm, gk = kc + kk;
            float v = 0.0f;
            if (gm < M && gk < K) {
                size_t o = (size_t)gm * K + gk;
                v = A_DYN ? ldf(A, o, bf) : ((const float*)A)[o];
            }
            As[kk][mm] = v;
        }
#pragma unroll
        for (int j = 0; j < 4; j++) {
            int idx = tid + j * 256;
            int nn = idx & 63, kk = idx >> 6;
            int gk = kc + kk, gn = n0 + nn;
            Bs[kk][nn] = (gk < K && gn < Nn) ? ldf(B, (size_t)gk * Nn + gn, bf) : 0.0f;
        }
        __syncthreads();
#pragma unroll
        for (int kk = 0; kk < 16; kk++) {
            float4 a4 = *(const float4*)&As[kk][ty * 4];
            float4 b4 = *(const float4*)&Bs[kk][tx * 4];
            float av[4] = {a4.x, a4.y, a4.z, a4.w};
            float bv[4] = {b4.x, b4.y, b4.z, b4.w};
#pragma unroll
            for (int i = 0; i < 4; i++)
#pragma unroll
                for (int j = 0; j < 4; j++) acc[i][j] += av[i] * bv[j];
        }
        __syncthreads();
    }

#pragma unroll
    for (int i = 0; i < 4; i++) {
        int m = m0 + ty * 4 + i;
        if (m >= M) continue;
        float sc = SCALE ? dinv[m] : 1.0f;
#pragma unroll
        for (int j = 0; j < 4; j++) {
            int n = n0 + tx * 4 + j;
            if (n >= Nn) continue;
            float v = acc[i][j];
            if (bias) v += ldf(bias, n, bf);
            if (SCALE) v *= sc;
            if (RELU) v = fmaxf(v, 0.0f);
            C[(size_t)m * Nn + n] = v;
        }
    }
}

// ---------- small GEMM3: h2p[N,16] = (H2[N,100] @ W2[100,16]) * dinv ----------
__global__ __launch_bounds__(256) void k_gemm3(const float* __restrict__ H2,
                                               const void* __restrict__ W2,
                                               const float* __restrict__ dinv,
                                               float* __restrict__ h2p,
                                               const int* __restrict__ flags) {
    __shared__ float Ws[H2D * CC];
    const int bf = flags[0];
    int tid = threadIdx.x;
    for (int i = tid; i < H2D * CC; i += 256) Ws[i] = ldf(W2, i, bf);
    __syncthreads();
    int n = tid & 15, r = tid >> 4;
    int row = blockIdx.x * 16 + r;
    if (row >= NN) return;
    const float* h = H2 + (size_t)row * H2D;
    float acc = 0.0f;
#pragma unroll 4
    for (int k = 0; k < H2D; k++) acc += h[k] * Ws[k * CC + n];
    h2p[(size_t)row * CC + n] = acc * dinv[row];
}

// ---------- aggregation 1 ----------
__global__ __launch_bounds__(128) void k_agg1(const float* __restrict__ h1p,
                                              const int* __restrict__ row_ptr,
                                              const int* __restrict__ csr_src,
                                              const float* __restrict__ dinv,
                                              const void* __restrict__ b1,
                                              float* __restrict__ H2,
                                              const int* __restrict__ flags) {
    int node = blockIdx.x;
    int f = threadIdx.x;
    if (f >= H2D) return;
    float acc = h1p[(size_t)node * H2D + f];  // self loop
    int lo = row_ptr[node], hi = row_ptr[node + 1];
    for (int e = lo; e < hi; e++) {
        int s = csr_src[e];
        acc += h1p[(size_t)s * H2D + f];
    }
    float v = acc * dinv[node] + ldf(b1, f, flags[0]);
    H2[(size_t)node * H2D + f] = fmaxf(v, 0.0f);
}

// ---------- aggregation 2 + bias + log_softmax ----------
__global__ __launch_bounds__(256) void k_agg2(const float* __restrict__ h2p,
                                              const int* __restrict__ row_ptr,
                                              const int* __restrict__ csr_src,
                                              const float* __restrict__ dinv,
                                              const void* __restrict__ b2,
                                              void* __restrict__ out,
                                              const int* __restrict__ flags) {
    int tid = threadIdx.x;
    int n = tid & 15;
    int g = tid >> 4;  // 16 nodes per block
    int node = blockIdx.x * 16 + g;
    if (node >= NN) return;
    const int bf = flags[0];
    float acc = h2p[(size_t)node * CC + n];  // self loop
    int lo = row_ptr[node], hi = row_ptr[node + 1];
    for (int e = lo; e < hi; e++) {
        acc += h2p[(size_t)csr_src[e] * CC + n];
    }
    float logit = acc * dinv[node] + ldf(b2, n, bf);
    float m = logit;
#pragma unroll
    for (int off = 1; off < 16; off <<= 1) m = fmaxf(m, __shfl_xor(m, off, 16));
    float ex = __expf(logit - m);
    float ssum = ex;
#pragma unroll
    for (int off = 1; off < 16; off <<= 1) ssum += __shfl_xor(ssum, off, 16);
    float r = logit - m - __logf(ssum);
    size_t oidx = (size_t)node * CC + n;
    if (bf) ((__hip_bfloat16*)out)[oidx] = __float2bfloat16(r);
    else    ((float*)out)[oidx] = r;
}

extern "C" void kernel_launch(void* const* d_in, const int* in_sizes, int n_in,
                              void* d_out, int out_size, void* d_ws, size_t ws_size,
                              hipStream_t stream) {
    const void* x     = d_in[0];
    const void* lin_W = d_in[1];
    const void* lin_b = d_in[2];
    const void* W1    = d_in[3];
    const void* b1    = d_in[4];
    const void* W2    = d_in[5];
    const void* b2    = d_in[6];
    const int*  ei    = (const int*)d_in[7];

    char* ws = (char*)d_ws;
    size_t off = 0;
    auto alloc = [&](size_t bytes) {
        off = (off + 255) & ~(size_t)255;
        void* p = ws + off;
        off += bytes;
        return p;
    };
    int*   flags   = (int*)alloc(2 * 4);
    int*   cnt     = (int*)alloc((size_t)NN * 4);
    int*   row_ptr = (int*)alloc((size_t)(NN + 1) * 4);
    int*   csr_src = (int*)alloc((size_t)EE * 4);
    float* dinv    = (float*)alloc((size_t)NN * 4);
    float* H1      = (float*)alloc((size_t)NN * H1D * 4);  // 60 MB
    float* H1p     = (float*)alloc((size_t)NN * H2D * 4);  // 20 MB
    float* H2      = (float*)alloc((size_t)NN * H2D * 4);  // 20 MB
    float* h2p     = (float*)alloc((size_t)NN * CC * 4);   // 3.2 MB

    const int gN = (NN + 255) / 256;
    const int gE = (EE + 255) / 256;

    k_sniff<<<1, 256, 0, stream>>>((const unsigned short*)x, (const unsigned int*)ei, flags);

    // CSR + degrees
    k_zero_cnt<<<gN, 256, 0, stream>>>(cnt);
    k_hist<<<gE, 256, 0, stream>>>(ei, cnt, flags);
    k_dinv<<<gN, 256, 0, stream>>>(cnt, dinv);
    k_scan<<<1, 1024, 0, stream>>>(cnt, row_ptr);
    k_scatter<<<gE, 256, 0, stream>>>(ei, row_ptr, cnt, csr_src, flags);

    // H1 = relu(x @ lin_W + lin_b)
    {
        dim3 grid((NN + 63) / 64, (H1D + 63) / 64);
        k_gemm<true, true, false><<<grid, 256, 0, stream>>>(
            x, lin_W, lin_b, nullptr, H1, NN, FIN, H1D, flags);
    }
    // H1p = (H1 @ W1) * dinv[row]
    {
        dim3 grid((NN + 63) / 64, (H2D + 63) / 64);
        k_gemm<false, false, true><<<grid, 256, 0, stream>>>(
            H1, W1, nullptr, dinv, H1p, NN, H1D, H2D, flags);
    }
    // H2 = relu(dinv * (gather-sum H1p) + b1)
    k_agg1<<<NN, 128, 0, stream>>>(H1p, row_ptr, csr_src, dinv, b1, H2, flags);
    // h2p = (H2 @ W2) * dinv[row]
    k_gemm3<<<(NN + 15) / 16, 256, 0, stream>>>(H2, W2, dinv, h2p, flags);
    // out = log_softmax(dinv * (gather-sum h2p) + b2)
    k_agg2<<<(NN + 15) / 16, 256, 0, stream>>>(h2p, row_ptr, csr_src, dinv, b2, d_out, flags);
}